// Round 4
// baseline (490.369 us; speedup 1.0000x reference)
//
#include <hip/hip_runtime.h>
#include <hip/hip_bf16.h>
#include <stdint.h>

#define B_ 4
#define S_ 2048
#define E_ 2048
#define H_ 16
#define D_ 128
#define M_ (B_ * S_)  // 8192 rows

typedef unsigned short ushort_t;
typedef unsigned int uint_t;
typedef __attribute__((ext_vector_type(4))) float f32x4;
typedef __attribute__((ext_vector_type(8))) short bf16x8;

__device__ __forceinline__ ushort_t f2bf(float f) {
  uint_t u = __float_as_uint(f);
  u += 0x7FFFu + ((u >> 16) & 1u);  // RNE
  return (ushort_t)(u >> 16);
}
__device__ __forceinline__ float bf2f(ushort_t h) {
  return __uint_as_float(((uint_t)h) << 16);
}
__device__ __forceinline__ uint_t cvt_pk_bf16(float lo, float hi) {
  uint_t r;
  asm("v_cvt_pk_bf16_f32 %0, %1, %2" : "=v"(r) : "v"(lo), "v"(hi));
  return r;
}

#define GLOAD_LDS16(gp, lp)                                   \
  __builtin_amdgcn_global_load_lds(                           \
      (__attribute__((address_space(1))) void*)(gp),          \
      (__attribute__((address_space(3))) void*)(lp), 16, 0, 0)

// ---------------------------------------------------------------- converts
__global__ void f32_to_bf16(const float* __restrict__ in, ushort_t* __restrict__ out,
                            size_t n4) {
  const size_t stride = (size_t)gridDim.x * blockDim.x;
  for (size_t i = (size_t)blockIdx.x * blockDim.x + threadIdx.x; i < n4; i += stride) {
    float4 f = ((const float4*)in)[i];
    uint_t lo = (uint_t)f2bf(f.x) | ((uint_t)f2bf(f.y) << 16);
    uint_t hi = (uint_t)f2bf(f.z) | ((uint_t)f2bf(f.w) << 16);
    ((uint2*)out)[i] = make_uint2(lo, hi);
  }
}

// ---------------------------------------------------------------- GEMM 256x256, BK=32, 8 waves
// C[M][N] = A[M][K] · Bw[N][K]^T + bias, with fused epilogues:
// MODE 0: bf16 store. MODE 1: f32 store. MODE 2: bf16 + RoPE. MODE 3: bf16 V-transpose.
// Pipeline: 4 LDS K-tile buffers (32KB each), stage 2 tiles ahead via global_load_lds,
// counted s_waitcnt vmcnt(4) + one s_barrier per K-tile -- loads never drain to 0.
// LDS layout: row-pairs (2 rows of 64B share a 128B line), chunk-XOR swizzle, 2-way max.
template <int MODE>
__global__ __launch_bounds__(512, 1) void gemm256(const ushort_t* __restrict__ A,
                                                  const ushort_t* __restrict__ Bw,
                                                  const float* __restrict__ bias,
                                                  void* __restrict__ Cv) {
  __shared__ __align__(16) char lds[131072];  // 4 bufs x (A 16KB + B 16KB)
  const int tid = threadIdx.x;
  const int w = tid >> 6, l = tid & 63, g = l >> 4, ln = l & 15;
  const int wm = w >> 2, wn = w & 3;

  // XCD-chunked bijective swizzle; 8 consecutive blocks share m-index AND xcd -> A panel L2-hot
  const int flat = blockIdx.x;  // 256 blocks
  const int swz = (flat & 7) * 32 + (flat >> 3);
  const int m0 = (swz >> 3) * 256, n0 = (swz & 7) * 256;

  const ushort_t* Ab = A + (size_t)m0 * E_;
  const ushort_t* Bb = Bw + (size_t)n0 * E_;

  // staging source offsets (lane-constant): dest byte c*16 (linear), source inverse-swizzled
  int srcOff[2];
#pragma unroll
  for (int i = 0; i < 2; i++) {
    const int c = i * 512 + tid;       // 0..1023 chunks of one 16KB region
    const int r2 = c >> 3;             // row-pair 0..127
    const int j = (c & 7) ^ (r2 & 7);  // source chunk
    const int par = j >> 2, cc = j & 3;
    srcOff[i] = (2 * r2 + par) * E_ + cc * 8;  // elements; add t*32 at use
  }

  const int NT = E_ / 32;  // 64 K-tiles

  auto STAGE = [&](int t_) {
    char* dst = lds + (t_ & 3) * 32768;
#pragma unroll
    for (int i = 0; i < 2; i++)
      GLOAD_LDS16(Ab + (size_t)(t_ * 32) + srcOff[i], dst + (i * 512 + w * 64) * 16);
#pragma unroll
    for (int i = 0; i < 2; i++)
      GLOAD_LDS16(Bb + (size_t)(t_ * 32) + srcOff[i], dst + 16384 + (i * 512 + w * 64) * 16);
  };

  // read-side LDS byte offsets (within a buffer): +mi*1024 / +ni*1024 walk fragments
  const int r2l = ln >> 1, parl = ln & 1;
  const int chunk = ((parl << 2) + g) ^ r2l;
  const int addrA0 = (wm * 64 + r2l) * 128 + chunk * 16;
  const int addrB0 = 16384 + (wn * 32 + r2l) * 128 + chunk * 16;

  f32x4 acc[8][4];
#pragma unroll
  for (int mi = 0; mi < 8; mi++)
#pragma unroll
    for (int ni = 0; ni < 4; ni++)
#pragma unroll
      for (int r = 0; r < 4; r++) acc[mi][ni][r] = 0.f;

  STAGE(0);
  STAGE(1);

  for (int t = 0; t < NT; t++) {
    // ensure tile t landed; keep tile t+1 (newest 4 loads) in flight
    if (t + 1 < NT)
      asm volatile("s_waitcnt vmcnt(4)" ::: "memory");
    else
      asm volatile("s_waitcnt vmcnt(0)" ::: "memory");
    __builtin_amdgcn_s_barrier();
    __builtin_amdgcn_sched_barrier(0);
    if (t + 2 < NT) STAGE(t + 2);

    const char* bufp = lds + (t & 3) * 32768;
    bf16x8 af[8], bfr[4];
#pragma unroll
    for (int mi = 0; mi < 8; mi++) af[mi] = *(const bf16x8*)(bufp + addrA0 + mi * 1024);
#pragma unroll
    for (int ni = 0; ni < 4; ni++) bfr[ni] = *(const bf16x8*)(bufp + addrB0 + ni * 1024);

    __builtin_amdgcn_s_setprio(1);
#pragma unroll
    for (int mi = 0; mi < 8; mi++)
#pragma unroll
      for (int ni = 0; ni < 4; ni++)
        acc[mi][ni] = __builtin_amdgcn_mfma_f32_16x16x32_bf16(af[mi], bfr[ni], acc[mi][ni], 0, 0, 0);
    __builtin_amdgcn_s_setprio(0);
  }

  // ---------------- epilogue
  float bv[4];
#pragma unroll
  for (int ni = 0; ni < 4; ni++) bv[ni] = bias[n0 + wn * 64 + ni * 16 + ln];

#pragma unroll
  for (int mi = 0; mi < 8; mi++)
#pragma unroll
    for (int ni = 0; ni < 4; ni++) {
      const int col = n0 + wn * 64 + ni * 16 + ln;
      const int row0 = m0 + wm * 128 + mi * 16 + g * 4;
      float v[4];
#pragma unroll
      for (int r = 0; r < 4; r++) v[r] = acc[mi][ni][r] + bv[ni];

      if (MODE == 1) {  // f32 out
        float* C = (float*)Cv;
#pragma unroll
        for (int r = 0; r < 4; r++) C[(size_t)(row0 + r) * E_ + col] = v[r];
      } else if (MODE == 2) {  // RoPE (pairs = adjacent cols = adjacent lanes)
        const int ip = (col & 127) >> 1;                     // pair index within head
        const float invf = exp2f(-0.20762050593046f * ip);   // 10000^(-2ip/128)
        const float sgn = (col & 1) ? 1.f : -1.f;
        ushort_t* C = (ushort_t*)Cv;
#pragma unroll
        for (int r = 0; r < 4; r++) {
          const int s = (row0 + r) & (S_ - 1);
          float sn, cs;
          sincosf((float)s * invf, &sn, &cs);
          const float p = __shfl_xor(v[r], 1);  // partner of the (even,odd) pair
          const float res = v[r] * cs + sgn * p * sn;
          C[(size_t)(row0 + r) * E_ + col] = f2bf(res);
        }
      } else if (MODE == 3) {  // V-transpose: Vt[((b*H+h)*D+d)*S + s]
        ushort_t* C = (ushort_t*)Cv;
        const int h = col >> 7, d = col & 127;
        const int b = row0 >> 11, s0 = row0 & (S_ - 1);
        const uint_t lo = cvt_pk_bf16(v[0], v[1]);
        const uint_t hi = cvt_pk_bf16(v[2], v[3]);
        *(uint2*)(C + (((size_t)(b * H_ + h) * D_ + d) * S_ + s0)) = make_uint2(lo, hi);
      } else {  // bf16 out
        ushort_t* C = (ushort_t*)Cv;
#pragma unroll
        for (int r = 0; r < 4; r++) C[(size_t)(row0 + r) * E_ + col] = f2bf(v[r]);
      }
    }
}

// ---------------------------------------------------------------- flash attention (causal)
// 256 thr / 4 waves, QBLK=128, KVBLK=64, balanced q-unit pairs, swapped QK^T,
// counted-vmcnt double-buffer K/V, defer-max, setprio around MFMA clusters.
__global__ __launch_bounds__(256, 2) void attn_fwd(const ushort_t* __restrict__ Q,
                                                   const ushort_t* __restrict__ K,
                                                   const ushort_t* __restrict__ Vt,
                                                   ushort_t* __restrict__ O) {
  const int b = blockIdx.z, h = blockIdx.y;
  const int pair = blockIdx.x;  // 0..7
  const int tid = threadIdx.x;
  const int w = tid >> 6, l = tid & 63, g = l >> 4, ln = l & 15;

  __shared__ ushort_t Ks[2][64 * 128];  // 32 KB
  __shared__ ushort_t Vs[2][128 * 64];  // 32 KB
  __shared__ ushort_t Ps[4][32 * 64];   // 16 KB, XOR-swizzled rows

  const ushort_t* Kb = K + (size_t)(b * S_) * E_ + h * D_;
  const ushort_t* Vb = Vt + (size_t)(b * H_ + h) * D_ * S_;
  const float scale = 0.08838834764831845f;  // D^-0.5

#define STAGE_KV(buf, kv0_)                                                      \
  do {                                                                           \
    _Pragma("unroll") for (int i = 0; i < 4; i++) {                              \
      const int c = i * 256 + tid;                                               \
      const int row = c >> 4, sl = c & 15;                                       \
      const int gs = sl ^ (row & 7);                                             \
      GLOAD_LDS16(Kb + (size_t)((kv0_) + row) * E_ + gs * 8,                     \
                  (char*)(&Ks[buf][0]) + (i * 256 + w * 64) * 16);               \
    }                                                                            \
    _Pragma("unroll") for (int i = 0; i < 4; i++) {                              \
      const int c = i * 256 + tid;                                               \
      const int row = c >> 3, sl = c & 7;                                        \
      const int gs = sl ^ (row & 7);                                             \
      GLOAD_LDS16(Vb + (size_t)row * S_ + (kv0_) + gs * 8,                       \
                  (char*)(&Vs[buf][0]) + (i * 256 + w * 64) * 16);               \
    }                                                                            \
  } while (0)

  for (int pass = 0; pass < 2; pass++) {
    const int u = (pass == 0) ? pair : (15 - pair);
    const int q0 = u * 128;
    const int wrow0 = q0 + w * 32;

    // Q fragments (B-operand layout: n=ln q-row, k=d), pre-scaled by 1/sqrt(D)
    bf16x8 qf[2][4];
    {
      const ushort_t* qb = Q + (size_t)(b * S_ + wrow0) * E_ + h * D_;
#pragma unroll
      for (int mi = 0; mi < 2; mi++)
#pragma unroll
        for (int kk = 0; kk < 4; kk++) {
          bf16x8 v = *(const bf16x8*)(qb + (size_t)(mi * 16 + ln) * E_ + kk * 32 + g * 8);
#pragma unroll
          for (int j = 0; j < 8; j++) v[j] = (short)f2bf(bf2f((ushort_t)v[j]) * scale);
          qf[mi][kk] = v;
        }
    }

    f32x4 oacc[2][8];
#pragma unroll
    for (int mi = 0; mi < 2; mi++)
#pragma unroll
      for (int nd = 0; nd < 8; nd++)
#pragma unroll
        for (int r = 0; r < 4; r++) oacc[mi][nd][r] = 0.f;
    float mrun[2], srun[2];
#pragma unroll
    for (int mi = 0; mi < 2; mi++) {
      mrun[mi] = -__builtin_inff();
      srun[mi] = 0.f;
    }

    const int ntu = 2 * u + 2;
    STAGE_KV(0, 0);

    for (int t = 0; t < ntu; t++) {
      const int kv0 = t * 64;
      const int cur = t & 1;
      if (t + 1 < ntu) {
        STAGE_KV(cur ^ 1, kv0 + 64);
        asm volatile("s_waitcnt vmcnt(8)" ::: "memory");  // tile t landed; t+1 in flight
      } else {
        asm volatile("s_waitcnt vmcnt(0)" ::: "memory");
      }
      __builtin_amdgcn_s_barrier();
      __builtin_amdgcn_sched_barrier(0);

      if (kv0 <= wrow0 + 31) {
        const ushort_t* Kst = &Ks[cur][0];
        const ushort_t* Vst = &Vs[cur][0];
        // ---- swapped QK^T: sa[mi][ni] = S^T frag [kv = ni*16+g*4+r][q = mi*16+ln]
        f32x4 sa[2][4];
#pragma unroll
        for (int mi = 0; mi < 2; mi++)
#pragma unroll
          for (int ni = 0; ni < 4; ni++)
#pragma unroll
            for (int r = 0; r < 4; r++) sa[mi][ni][r] = 0.f;
        __builtin_amdgcn_s_setprio(1);
#pragma unroll
        for (int kk = 0; kk < 4; kk++) {
          bf16x8 kf[4];
#pragma unroll
          for (int ni = 0; ni < 4; ni++) {
            const int row = ni * 16 + ln;
            const int sl = (kk * 4 + g) ^ (row & 7);
            kf[ni] = *(const bf16x8*)(Kst + row * 128 + sl * 8);
          }
#pragma unroll
          for (int mi = 0; mi < 2; mi++)
#pragma unroll
            for (int ni = 0; ni < 4; ni++)
              sa[mi][ni] =
                  __builtin_amdgcn_mfma_f32_16x16x32_bf16(kf[ni], qf[mi][kk], sa[mi][ni], 0, 0, 0);
        }
        __builtin_amdgcn_s_setprio(0);
        // ---- causal mask (diagonal tiles only)
        if (kv0 + 63 > wrow0) {
#pragma unroll
          for (int mi = 0; mi < 2; mi++) {
            const int lim = wrow0 + mi * 16 + ln - kv0;
#pragma unroll
            for (int ni = 0; ni < 4; ni++)
#pragma unroll
              for (int r = 0; r < 4; r++)
                if (ni * 16 + g * 4 + r > lim) sa[mi][ni][r] = -__builtin_inff();
          }
        }
        // ---- softmax per q-row
#pragma unroll
        for (int mi = 0; mi < 2; mi++) {
          float vmax = -__builtin_inff();
#pragma unroll
          for (int ni = 0; ni < 4; ni++)
#pragma unroll
            for (int r = 0; r < 4; r++) vmax = fmaxf(vmax, sa[mi][ni][r]);
          vmax = fmaxf(vmax, __shfl_xor(vmax, 16));
          vmax = fmaxf(vmax, __shfl_xor(vmax, 32));
          if (!__all(vmax - mrun[mi] <= 8.0f)) {  // T13 defer-max
            const float mnew = fmaxf(mrun[mi], vmax);
            const float fs = __expf(mrun[mi] - mnew);
            mrun[mi] = mnew;
            srun[mi] *= fs;
#pragma unroll
            for (int nd = 0; nd < 8; nd++)
#pragma unroll
              for (int r = 0; r < 4; r++) oacc[mi][nd][r] *= fs;
          }
          const float m = mrun[mi];
          float psum = 0.f;
#pragma unroll
          for (int ni = 0; ni < 4; ni++) {
            float p0 = __expf(sa[mi][ni][0] - m);
            float p1 = __expf(sa[mi][ni][1] - m);
            float p2 = __expf(sa[mi][ni][2] - m);
            float p3 = __expf(sa[mi][ni][3] - m);
            psum += (p0 + p1) + (p2 + p3);
            const int byteW =
                (((mi * 16 + ln) * 64 + ni * 16 + g * 4) * 2) ^ ((ln & 7) << 4);
            *(uint2*)((char*)(&Ps[w][0]) + byteW) =
                make_uint2(cvt_pk_bf16(p0, p1), cvt_pk_bf16(p2, p3));
          }
          psum += __shfl_xor(psum, 16);
          psum += __shfl_xor(psum, 32);
          srun[mi] += psum;
        }
        asm volatile("s_waitcnt lgkmcnt(0)" ::: "memory");  // per-wave P write->read
        __builtin_amdgcn_sched_barrier(0);
        // ---- PV
        __builtin_amdgcn_s_setprio(1);
#pragma unroll
        for (int ks = 0; ks < 2; ks++) {
          bf16x8 pf[2];
#pragma unroll
          for (int mi = 0; mi < 2; mi++) {
            const int byteR =
                (((mi * 16 + ln) * 64 + ks * 32 + g * 8) * 2) ^ ((ln & 7) << 4);
            pf[mi] = *(const bf16x8*)((const char*)(&Ps[w][0]) + byteR);
          }
#pragma unroll
          for (int nd = 0; nd < 8; nd++) {
            const int row = nd * 16 + ln;
            const int sl = (ks * 4 + g) ^ (row & 7);
            const bf16x8 vf = *(const bf16x8*)(Vst + row * 64 + sl * 8);
#pragma unroll
            for (int mi = 0; mi < 2; mi++)
              oacc[mi][nd] =
                  __builtin_amdgcn_mfma_f32_16x16x32_bf16(vf, pf[mi], oacc[mi][nd], 0, 0, 0);
          }
        }
        __builtin_amdgcn_s_setprio(0);
      }
      __builtin_amdgcn_s_barrier();
    }

    // ---- epilogue
    {
      ushort_t* Ob = O + (size_t)(b * S_ + q0 + w * 32) * E_ + h * D_;
#pragma unroll
      for (int mi = 0; mi < 2; mi++) {
        const float inv = 1.0f / srun[mi];
#pragma unroll
        for (int nd = 0; nd < 8; nd++) {
          const uint_t lo = cvt_pk_bf16(oacc[mi][nd][0] * inv, oacc[mi][nd][1] * inv);
          const uint_t hi = cvt_pk_bf16(oacc[mi][nd][2] * inv, oacc[mi][nd][3] * inv);
          *(uint2*)(Ob + (size_t)(mi * 16 + ln) * E_ + nd * 16 + g * 4) = make_uint2(lo, hi);
        }
      }
    }
  }
#undef STAGE_KV
}

// ---------------------------------------------------------------- launch
extern "C" void kernel_launch(void* const* d_in, const int* in_sizes, int n_in,
                              void* d_out, int out_size, void* d_ws, size_t ws_size,
                              hipStream_t stream) {
  const float* x = (const float*)d_in[0];
  const float* Wq = (const float*)d_in[1];
  const float* bq = (const float*)d_in[2];
  const float* Wk = (const float*)d_in[3];
  const float* bk = (const float*)d_in[4];
  const float* Wv = (const float*)d_in[5];
  const float* bv = (const float*)d_in[6];
  const float* Wo = (const float*)d_in[7];
  const float* bo = (const float*)d_in[8];
  float* out = (float*)d_out;

  ushort_t* ws = (ushort_t*)d_ws;
  const size_t SZ = (size_t)M_ * E_;   // 16,777,216
  const size_t WSZ = (size_t)E_ * E_;  // 4,194,304
  ushort_t* xb = ws;            // x bf16; reused as attention output after projections
  ushort_t* Qb = ws + SZ;
  ushort_t* Kb = ws + 2 * SZ;
  ushort_t* Vtb = ws + 4 * SZ;  // [B][H][D][S], written directly by V-GEMM epilogue
  ushort_t* Wqb = ws + 5 * SZ;
  ushort_t* Wkb = Wqb + WSZ;
  ushort_t* Wvb = Wkb + WSZ;
  ushort_t* Wob = Wvb + WSZ;
  ushort_t* Ob = xb;

  f32_to_bf16<<<2048, 256, 0, stream>>>(x, xb, SZ / 4);
  f32_to_bf16<<<1024, 256, 0, stream>>>(Wq, Wqb, WSZ / 4);
  f32_to_bf16<<<1024, 256, 0, stream>>>(Wk, Wkb, WSZ / 4);
  f32_to_bf16<<<1024, 256, 0, stream>>>(Wv, Wvb, WSZ / 4);
  f32_to_bf16<<<1024, 256, 0, stream>>>(Wo, Wob, WSZ / 4);

  gemm256<2><<<256, 512, 0, stream>>>(xb, Wqb, bq, Qb);          // Q proj + RoPE
  gemm256<2><<<256, 512, 0, stream>>>(xb, Wkb, bk, Kb);          // K proj + RoPE
  gemm256<3><<<256, 512, 0, stream>>>(xb, Wvb, bv, Vtb);         // V proj + transpose

  attn_fwd<<<dim3(8, H_, B_), 256, 0, stream>>>(Qb, Kb, Vtb, Ob);

  gemm256<1><<<256, 512, 0, stream>>>(Ob, Wob, bo, (void*)out);  // out proj, f32
}

// Round 5
// 489.771 us; speedup vs baseline: 1.0012x; 1.0012x over previous
//
#include <hip/hip_runtime.h>
#include <hip/hip_bf16.h>
#include <stdint.h>

#define B_ 4
#define S_ 2048
#define E_ 2048
#define H_ 16
#define D_ 128
#define M_ (B_ * S_)  // 8192 rows

typedef unsigned short ushort_t;
typedef unsigned int uint_t;
typedef __attribute__((ext_vector_type(4))) float f32x4;
typedef __attribute__((ext_vector_type(2))) uint_t u32x2;
typedef __attribute__((ext_vector_type(8))) short bf16x8;

__device__ __forceinline__ ushort_t f2bf(float f) {
  uint_t u = __float_as_uint(f);
  u += 0x7FFFu + ((u >> 16) & 1u);  // RNE
  return (ushort_t)(u >> 16);
}
__device__ __forceinline__ float bf2f(ushort_t h) {
  return __uint_as_float(((uint_t)h) << 16);
}
__device__ __forceinline__ uint_t cvt_pk_bf16(float lo, float hi) {
  uint_t r;
  asm("v_cvt_pk_bf16_f32 %0, %1, %2" : "=v"(r) : "v"(lo), "v"(hi));
  return r;
}

#define GLOAD_LDS16(gp, lp)                                   \
  __builtin_amdgcn_global_load_lds(                           \
      (__attribute__((address_space(1))) void*)(gp),          \
      (__attribute__((address_space(3))) void*)(lp), 16, 0, 0)

// ---------------------------------------------------------------- converts (non-temporal:
// keep L2/L3 clean so the following GEMM doesn't hit cross-XCD dirty lines)
__global__ void f32_to_bf16(const float* __restrict__ in, ushort_t* __restrict__ out,
                            size_t n4) {
  const size_t stride = (size_t)gridDim.x * blockDim.x;
  for (size_t i = (size_t)blockIdx.x * blockDim.x + threadIdx.x; i < n4; i += stride) {
    const f32x4 f = __builtin_nontemporal_load((const f32x4*)in + i);
    u32x2 o;
    o[0] = (uint_t)f2bf(f[0]) | ((uint_t)f2bf(f[1]) << 16);
    o[1] = (uint_t)f2bf(f[2]) | ((uint_t)f2bf(f[3]) << 16);
    __builtin_nontemporal_store(o, (u32x2*)out + i);
  }
}

// ---------------------------------------------------------------- GEMM 256x256, BK=32, 8 waves
// C[M][N] = A[M][K] · Bw[N][K]^T + bias, with fused epilogues:
// MODE 1: f32 store (nt). MODE 2: bf16 + RoPE. MODE 3: bf16 V-transpose.
// Pipeline: 4 LDS K-tile buffers (32KB each), stage 2 tiles ahead via global_load_lds,
// counted s_waitcnt vmcnt(4) + one s_barrier per K-tile -- loads never drain to 0.
template <int MODE>
__global__ __launch_bounds__(512, 1) void gemm256(const ushort_t* __restrict__ A,
                                                  const ushort_t* __restrict__ Bw,
                                                  const float* __restrict__ bias,
                                                  void* __restrict__ Cv) {
  __shared__ __align__(16) char lds[131072];  // 4 bufs x (A 16KB + B 16KB)
  const int tid = threadIdx.x;
  const int w = tid >> 6, l = tid & 63, g = l >> 4, ln = l & 15;
  const int wm = w >> 2, wn = w & 3;

  // XCD-chunked bijective swizzle; blocks sharing an A-panel land on one XCD
  const int flat = blockIdx.x;  // 256 blocks
  const int swz = (flat & 7) * 32 + (flat >> 3);
  const int m0 = (swz >> 3) * 256, n0 = (swz & 7) * 256;

  const ushort_t* Ab = A + (size_t)m0 * E_;
  const ushort_t* Bb = Bw + (size_t)n0 * E_;

  int srcOff[2];
#pragma unroll
  for (int i = 0; i < 2; i++) {
    const int c = i * 512 + tid;       // 0..1023 chunks of one 16KB region
    const int r2 = c >> 3;             // row-pair 0..127
    const int j = (c & 7) ^ (r2 & 7);  // source chunk (inverse swizzle)
    const int par = j >> 2, cc = j & 3;
    srcOff[i] = (2 * r2 + par) * E_ + cc * 8;
  }

  const int NT = E_ / 32;  // 64 K-tiles

  auto STAGE = [&](int t_) {
    char* dst = lds + (t_ & 3) * 32768;
#pragma unroll
    for (int i = 0; i < 2; i++)
      GLOAD_LDS16(Ab + (size_t)(t_ * 32) + srcOff[i], dst + (i * 512 + w * 64) * 16);
#pragma unroll
    for (int i = 0; i < 2; i++)
      GLOAD_LDS16(Bb + (size_t)(t_ * 32) + srcOff[i], dst + 16384 + (i * 512 + w * 64) * 16);
  };

  const int r2l = ln >> 1, parl = ln & 1;
  const int chunk = ((parl << 2) + g) ^ r2l;
  const int addrA0 = (wm * 64 + r2l) * 128 + chunk * 16;
  const int addrB0 = 16384 + (wn * 32 + r2l) * 128 + chunk * 16;

  f32x4 acc[8][4];
#pragma unroll
  for (int mi = 0; mi < 8; mi++)
#pragma unroll
    for (int ni = 0; ni < 4; ni++)
#pragma unroll
      for (int r = 0; r < 4; r++) acc[mi][ni][r] = 0.f;

  STAGE(0);
  STAGE(1);

  for (int t = 0; t < NT; t++) {
    if (t + 1 < NT)
      asm volatile("s_waitcnt vmcnt(4)" ::: "memory");
    else
      asm volatile("s_waitcnt vmcnt(0)" ::: "memory");
    __builtin_amdgcn_s_barrier();
    __builtin_amdgcn_sched_barrier(0);
    if (t + 2 < NT) STAGE(t + 2);

    const char* bufp = lds + (t & 3) * 32768;
    bf16x8 af[8], bfr[4];
#pragma unroll
    for (int mi = 0; mi < 8; mi++) af[mi] = *(const bf16x8*)(bufp + addrA0 + mi * 1024);
#pragma unroll
    for (int ni = 0; ni < 4; ni++) bfr[ni] = *(const bf16x8*)(bufp + addrB0 + ni * 1024);

    __builtin_amdgcn_s_setprio(1);
#pragma unroll
    for (int mi = 0; mi < 8; mi++)
#pragma unroll
      for (int ni = 0; ni < 4; ni++)
        acc[mi][ni] = __builtin_amdgcn_mfma_f32_16x16x32_bf16(af[mi], bfr[ni], acc[mi][ni], 0, 0, 0);
    __builtin_amdgcn_s_setprio(0);
  }

  // ---------------- epilogue
  float bv[4];
#pragma unroll
  for (int ni = 0; ni < 4; ni++) bv[ni] = bias[n0 + wn * 64 + ni * 16 + ln];

#pragma unroll
  for (int mi = 0; mi < 8; mi++)
#pragma unroll
    for (int ni = 0; ni < 4; ni++) {
      const int col = n0 + wn * 64 + ni * 16 + ln;
      const int row0 = m0 + wm * 128 + mi * 16 + g * 4;
      float v[4];
#pragma unroll
      for (int r = 0; r < 4; r++) v[r] = acc[mi][ni][r] + bv[ni];

      if (MODE == 1) {  // f32 out, non-temporal (final output, never re-read on-chip)
        float* C = (float*)Cv;
#pragma unroll
        for (int r = 0; r < 4; r++)
          __builtin_nontemporal_store(v[r], C + (size_t)(row0 + r) * E_ + col);
      } else if (MODE == 2) {  // RoPE (pairs = adjacent cols = adjacent lanes)
        const int ip = (col & 127) >> 1;                     // pair index within head
        const float invf = exp2f(-0.20762050593046f * ip);   // 10000^(-2ip/128)
        const float sgn = (col & 1) ? 1.f : -1.f;
        ushort_t* C = (ushort_t*)Cv;
#pragma unroll
        for (int r = 0; r < 4; r++) {
          const int s = (row0 + r) & (S_ - 1);
          float sn, cs;
          sincosf((float)s * invf, &sn, &cs);
          const float p = __shfl_xor(v[r], 1);  // partner of the (even,odd) pair
          const float res = v[r] * cs + sgn * p * sn;
          C[(size_t)(row0 + r) * E_ + col] = f2bf(res);
        }
      } else if (MODE == 3) {  // V-transpose: Vt[((b*H+h)*D+d)*S + s]
        ushort_t* C = (ushort_t*)Cv;
        const int h = col >> 7, d = col & 127;
        const int b = row0 >> 11, s0 = row0 & (S_ - 1);
        const uint_t lo = cvt_pk_bf16(v[0], v[1]);
        const uint_t hi = cvt_pk_bf16(v[2], v[3]);
        *(uint2*)(C + (((size_t)(b * H_ + h) * D_ + d) * S_ + s0)) = make_uint2(lo, hi);
      }
    }
}

// ---------------------------------------------------------------- flash attention (causal)
// 256 thr / 4 waves, QBLK=128, KVBLK=64, balanced q-unit pairs, swapped QK^T,
// counted-vmcnt double-buffer K/V, defer-max, setprio.
// Grid: flat 512 blocks; bh = flat&63 -> all 8 pair-blocks of one (b,h) share
// flat%8 (same XCD) -> KV slice stays L2-resident.
__global__ __launch_bounds__(256, 2) void attn_fwd(const ushort_t* __restrict__ Q,
                                                   const ushort_t* __restrict__ K,
                                                   const ushort_t* __restrict__ Vt,
                                                   ushort_t* __restrict__ O) {
  const int flat = blockIdx.x;
  const int pair = flat >> 6;   // 0..7
  const int bh = flat & 63;     // XCD = bh%8 for all 8 pairs of this bh
  const int b = bh >> 4, h = bh & 15;
  const int tid = threadIdx.x;
  const int w = tid >> 6, l = tid & 63, g = l >> 4, ln = l & 15;

  __shared__ ushort_t Ks[2][64 * 128];  // 32 KB
  __shared__ ushort_t Vs[2][128 * 64];  // 32 KB
  __shared__ ushort_t Ps[4][32 * 64];   // 16 KB, XOR-swizzled rows

  const ushort_t* Kb = K + (size_t)(b * S_) * E_ + h * D_;
  const ushort_t* Vb = Vt + (size_t)(b * H_ + h) * D_ * S_;
  const float scale = 0.08838834764831845f;  // D^-0.5

#define STAGE_KV(buf, kv0_)                                                      \
  do {                                                                           \
    _Pragma("unroll") for (int i = 0; i < 4; i++) {                              \
      const int c = i * 256 + tid;                                               \
      const int row = c >> 4, sl = c & 15;                                       \
      const int gs = sl ^ (row & 7);                                             \
      GLOAD_LDS16(Kb + (size_t)((kv0_) + row) * E_ + gs * 8,                     \
                  (char*)(&Ks[buf][0]) + (i * 256 + w * 64) * 16);               \
    }                                                                            \
    _Pragma("unroll") for (int i = 0; i < 4; i++) {                              \
      const int c = i * 256 + tid;                                               \
      const int row = c >> 3, sl = c & 7;                                        \
      const int gs = sl ^ (row & 7);                                             \
      GLOAD_LDS16(Vb + (size_t)row * S_ + (kv0_) + gs * 8,                       \
                  (char*)(&Vs[buf][0]) + (i * 256 + w * 64) * 16);               \
    }                                                                            \
  } while (0)

  for (int pass = 0; pass < 2; pass++) {
    const int u = (pass == 0) ? pair : (15 - pair);
    const int q0 = u * 128;
    const int wrow0 = q0 + w * 32;

    bf16x8 qf[2][4];
    {
      const ushort_t* qb = Q + (size_t)(b * S_ + wrow0) * E_ + h * D_;
#pragma unroll
      for (int mi = 0; mi < 2; mi++)
#pragma unroll
        for (int kk = 0; kk < 4; kk++) {
          bf16x8 v = *(const bf16x8*)(qb + (size_t)(mi * 16 + ln) * E_ + kk * 32 + g * 8);
#pragma unroll
          for (int j = 0; j < 8; j++) v[j] = (short)f2bf(bf2f((ushort_t)v[j]) * scale);
          qf[mi][kk] = v;
        }
    }

    f32x4 oacc[2][8];
#pragma unroll
    for (int mi = 0; mi < 2; mi++)
#pragma unroll
      for (int nd = 0; nd < 8; nd++)
#pragma unroll
        for (int r = 0; r < 4; r++) oacc[mi][nd][r] = 0.f;
    float mrun[2], srun[2];
#pragma unroll
    for (int mi = 0; mi < 2; mi++) {
      mrun[mi] = -__builtin_inff();
      srun[mi] = 0.f;
    }

    const int ntu = 2 * u + 2;
    STAGE_KV(0, 0);

    for (int t = 0; t < ntu; t++) {
      const int kv0 = t * 64;
      const int cur = t & 1;
      if (t + 1 < ntu) {
        STAGE_KV(cur ^ 1, kv0 + 64);
        asm volatile("s_waitcnt vmcnt(8)" ::: "memory");  // tile t landed; t+1 in flight
      } else {
        asm volatile("s_waitcnt vmcnt(0)" ::: "memory");
      }
      __builtin_amdgcn_s_barrier();
      __builtin_amdgcn_sched_barrier(0);

      if (kv0 <= wrow0 + 31) {
        const ushort_t* Kst = &Ks[cur][0];
        const ushort_t* Vst = &Vs[cur][0];
        f32x4 sa[2][4];
#pragma unroll
        for (int mi = 0; mi < 2; mi++)
#pragma unroll
          for (int ni = 0; ni < 4; ni++)
#pragma unroll
            for (int r = 0; r < 4; r++) sa[mi][ni][r] = 0.f;
        __builtin_amdgcn_s_setprio(1);
#pragma unroll
        for (int kk = 0; kk < 4; kk++) {
          bf16x8 kf[4];
#pragma unroll
          for (int ni = 0; ni < 4; ni++) {
            const int row = ni * 16 + ln;
            const int sl = (kk * 4 + g) ^ (row & 7);
            kf[ni] = *(const bf16x8*)(Kst + row * 128 + sl * 8);
          }
#pragma unroll
          for (int mi = 0; mi < 2; mi++)
#pragma unroll
            for (int ni = 0; ni < 4; ni++)
              sa[mi][ni] =
                  __builtin_amdgcn_mfma_f32_16x16x32_bf16(kf[ni], qf[mi][kk], sa[mi][ni], 0, 0, 0);
        }
        __builtin_amdgcn_s_setprio(0);
        if (kv0 + 63 > wrow0) {
#pragma unroll
          for (int mi = 0; mi < 2; mi++) {
            const int lim = wrow0 + mi * 16 + ln - kv0;
#pragma unroll
            for (int ni = 0; ni < 4; ni++)
#pragma unroll
              for (int r = 0; r < 4; r++)
                if (ni * 16 + g * 4 + r > lim) sa[mi][ni][r] = -__builtin_inff();
          }
        }
#pragma unroll
        for (int mi = 0; mi < 2; mi++) {
          float vmax = -__builtin_inff();
#pragma unroll
          for (int ni = 0; ni < 4; ni++)
#pragma unroll
            for (int r = 0; r < 4; r++) vmax = fmaxf(vmax, sa[mi][ni][r]);
          vmax = fmaxf(vmax, __shfl_xor(vmax, 16));
          vmax = fmaxf(vmax, __shfl_xor(vmax, 32));
          if (!__all(vmax - mrun[mi] <= 8.0f)) {  // T13 defer-max
            const float mnew = fmaxf(mrun[mi], vmax);
            const float fs = __expf(mrun[mi] - mnew);
            mrun[mi] = mnew;
            srun[mi] *= fs;
#pragma unroll
            for (int nd = 0; nd < 8; nd++)
#pragma unroll
              for (int r = 0; r < 4; r++) oacc[mi][nd][r] *= fs;
          }
          const float m = mrun[mi];
          float psum = 0.f;
#pragma unroll
          for (int ni = 0; ni < 4; ni++) {
            float p0 = __expf(sa[mi][ni][0] - m);
            float p1 = __expf(sa[mi][ni][1] - m);
            float p2 = __expf(sa[mi][ni][2] - m);
            float p3 = __expf(sa[mi][ni][3] - m);
            psum += (p0 + p1) + (p2 + p3);
            const int byteW =
                (((mi * 16 + ln) * 64 + ni * 16 + g * 4) * 2) ^ ((ln & 7) << 4);
            *(uint2*)((char*)(&Ps[w][0]) + byteW) =
                make_uint2(cvt_pk_bf16(p0, p1), cvt_pk_bf16(p2, p3));
          }
          psum += __shfl_xor(psum, 16);
          psum += __shfl_xor(psum, 32);
          srun[mi] += psum;
        }
        asm volatile("s_waitcnt lgkmcnt(0)" ::: "memory");  // per-wave P write->read
        __builtin_amdgcn_sched_barrier(0);
        __builtin_amdgcn_s_setprio(1);
#pragma unroll
        for (int ks = 0; ks < 2; ks++) {
          bf16x8 pf[2];
#pragma unroll
          for (int mi = 0; mi < 2; mi++) {
            const int byteR =
                (((mi * 16 + ln) * 64 + ks * 32 + g * 8) * 2) ^ ((ln & 7) << 4);
            pf[mi] = *(const bf16x8*)((const char*)(&Ps[w][0]) + byteR);
          }
#pragma unroll
          for (int nd = 0; nd < 8; nd++) {
            const int row = nd * 16 + ln;
            const int sl = (ks * 4 + g) ^ (row & 7);
            const bf16x8 vf = *(const bf16x8*)(Vst + row * 64 + sl * 8);
#pragma unroll
            for (int mi = 0; mi < 2; mi++)
              oacc[mi][nd] =
                  __builtin_amdgcn_mfma_f32_16x16x32_bf16(vf, pf[mi], oacc[mi][nd], 0, 0, 0);
          }
        }
        __builtin_amdgcn_s_setprio(0);
      }
      __builtin_amdgcn_s_barrier();
    }

    // ---- epilogue
    {
      ushort_t* Ob = O + (size_t)(b * S_ + q0 + w * 32) * E_ + h * D_;
#pragma unroll
      for (int mi = 0; mi < 2; mi++) {
        const float inv = 1.0f / srun[mi];
#pragma unroll
        for (int nd = 0; nd < 8; nd++) {
          const uint_t lo = cvt_pk_bf16(oacc[mi][nd][0] * inv, oacc[mi][nd][1] * inv);
          const uint_t hi = cvt_pk_bf16(oacc[mi][nd][2] * inv, oacc[mi][nd][3] * inv);
          *(uint2*)(Ob + (size_t)(mi * 16 + ln) * E_ + nd * 16 + g * 4) = make_uint2(lo, hi);
        }
      }
    }
  }
#undef STAGE_KV
}

// ---------------------------------------------------------------- launch
extern "C" void kernel_launch(void* const* d_in, const int* in_sizes, int n_in,
                              void* d_out, int out_size, void* d_ws, size_t ws_size,
                              hipStream_t stream) {
  const float* x = (const float*)d_in[0];
  const float* Wq = (const float*)d_in[1];
  const float* bq = (const float*)d_in[2];
  const float* Wk = (const float*)d_in[3];
  const float* bk = (const float*)d_in[4];
  const float* Wv = (const float*)d_in[5];
  const float* bv = (const float*)d_in[6];
  const float* Wo = (const float*)d_in[7];
  const float* bo = (const float*)d_in[8];
  float* out = (float*)d_out;

  ushort_t* ws = (ushort_t*)d_ws;
  const size_t SZ = (size_t)M_ * E_;   // 16,777,216
  const size_t WSZ = (size_t)E_ * E_;  // 4,194,304
  ushort_t* xb = ws;            // x bf16; reused as attention output after projections
  ushort_t* Qb = ws + SZ;
  ushort_t* Kb = ws + 2 * SZ;
  ushort_t* Vtb = ws + 4 * SZ;  // [B][H][D][S], written directly by V-GEMM epilogue
  ushort_t* Wqb = ws + 5 * SZ;
  ushort_t* Wkb = Wqb + WSZ;
  ushort_t* Wvb = Wkb + WSZ;
  ushort_t* Wob = Wvb + WSZ;
  ushort_t* Ob = xb;

  f32_to_bf16<<<2048, 256, 0, stream>>>(x, xb, SZ / 4);
  f32_to_bf16<<<1024, 256, 0, stream>>>(Wq, Wqb, WSZ / 4);
  f32_to_bf16<<<1024, 256, 0, stream>>>(Wk, Wkb, WSZ / 4);
  f32_to_bf16<<<1024, 256, 0, stream>>>(Wv, Wvb, WSZ / 4);
  f32_to_bf16<<<1024, 256, 0, stream>>>(Wo, Wob, WSZ / 4);

  gemm256<2><<<256, 512, 0, stream>>>(xb, Wqb, bq, Qb);          // Q proj + RoPE
  gemm256<2><<<256, 512, 0, stream>>>(xb, Wkb, bk, Kb);          // K proj + RoPE
  gemm256<3><<<256, 512, 0, stream>>>(xb, Wvb, bv, Vtb);         // V proj + transpose

  attn_fwd<<<512, 256, 0, stream>>>(Qb, Kb, Vtb, Ob);

  gemm256<1><<<256, 512, 0, stream>>>(Ob, Wob, bo, (void*)out);  // out proj, f32
}